// Round 15
// baseline (2401.583 us; speedup 1.0000x reference)
//
#include <hip/hip_runtime.h>

// DIMKT round 14: R13 + one-step-ahead gather pipeline + drain overlap.
//   Gather set G(t) (xs/kbias/cis @ t, xv @ t+1) prefetched during step t-1's
//   barrier-2 shadow (2 named sets, unroll-2). P1: sdf stores issued before
//   gamma pass (ack hidden under MFMAs). Protocol identical to R13:
//   sc1 IF$ data plane, agent-atomic 64B-padded slot barrier, LDS panel dedup.

typedef unsigned short u16;
using f32x4 = __attribute__((ext_vector_type(4))) float;
using bf16x8 = __attribute__((ext_vector_type(8))) short;

#define DEV static __device__ __forceinline__

#define Bv 512
#define Sv 200

DEV u16 f2bf(float f) {
  unsigned int u = __float_as_uint(f);
  unsigned int r = (u + 0x7fffu + ((u >> 16) & 1u)) >> 16;
  return (u16)r;
}
DEV float bf2f(u16 h) { return __uint_as_float(((unsigned int)h) << 16); }
DEV float sigm(float x) { return 1.0f / (1.0f + __expf(-x)); }
DEV float tanh_(float x) {
  x = fmaxf(fminf(x, 15.f), -15.f);
  float e = __expf(2.0f * x);
  return (e - 1.0f) / (e + 1.0f);
}
DEV f32x4 MF(bf16x8 a, bf16x8 b, f32x4 c) {
  return __builtin_amdgcn_mfma_f32_16x16x32_bf16(a, b, c, 0, 0, 0);
}

// ---- pipelined agent-scope (sc1) data plane (R7..R13-proven) ----
union LDU { f32x4 f; bf16x8 b; };
DEV void ld16v(f32x4* d, const u16* p) {  // issue; NO wait
  asm volatile("global_load_dwordx4 %0, %1, off sc1" : "=v"(*d) : "v"(p));
}
DEV void st2v(u16* p, u16 v) {  // write-through to coherence point
  unsigned w = v;
  asm volatile("global_store_short %0, %1, off sc1" : : "v"(p), "v"(w) : "memory");
}
DEV void waitv0() {
  asm volatile("s_waitcnt vmcnt(0)" ::: "memory");
  __builtin_amdgcn_sched_barrier(0);  // rule #18
}

// ================= precompute machinery (round-0, verified) =================
template <int NB, bool AF32>
DEV void gemm_tiles(const void* __restrict__ Aptr, int mvalid,
                    const u16* __restrict__ BT0, const u16* __restrict__ BT1,
                    u16* ldsA, u16* ldsB0, u16* ldsB1, int tid,
                    f32x4* acc0, f32x4* acc1) {
  const int lane = tid & 63, wid = tid >> 6;
  const int fr = lane & 15, fq = lane >> 4;
  const int srow = tid >> 2, sseg = tid & 3;

  for (int kt = 0; kt < 16; ++kt) {
    const int k0 = kt * 32;
    {
      bf16x8 pack;
      if constexpr (AF32) {
        if (srow < mvalid) {
          const float4* ap = (const float4*)((const float*)Aptr + (size_t)srow * 512 + k0 + sseg * 8);
          float4 v0 = ap[0], v1 = ap[1];
          pack[0] = (short)f2bf(v0.x); pack[1] = (short)f2bf(v0.y);
          pack[2] = (short)f2bf(v0.z); pack[3] = (short)f2bf(v0.w);
          pack[4] = (short)f2bf(v1.x); pack[5] = (short)f2bf(v1.y);
          pack[6] = (short)f2bf(v1.z); pack[7] = (short)f2bf(v1.w);
        } else {
          for (int j = 0; j < 8; ++j) pack[j] = 0;
        }
      } else {
        pack = *(const bf16x8*)((const u16*)Aptr + (size_t)srow * 512 + k0 + sseg * 8);
      }
      *(bf16x8*)&ldsA[srow * 40 + sseg * 8] = pack;
      *(bf16x8*)&ldsB0[srow * 40 + sseg * 8] =
          *(const bf16x8*)(BT0 + (size_t)srow * 512 + k0 + sseg * 8);
      if constexpr (NB == 2)
        *(bf16x8*)&ldsB1[srow * 40 + sseg * 8] =
            *(const bf16x8*)(BT1 + (size_t)srow * 512 + k0 + sseg * 8);
    }
    __syncthreads();
    bf16x8 a = *(const bf16x8*)&ldsA[(wid * 16 + fr) * 40 + fq * 8];
#pragma unroll
    for (int ni = 0; ni < 4; ++ni) {
      bf16x8 b0 = *(const bf16x8*)&ldsB0[(ni * 16 + fr) * 40 + fq * 8];
      acc0[ni] = MF(a, b0, acc0[ni]);
      if constexpr (NB == 2) {
        bf16x8 b1 = *(const bf16x8*)&ldsB1[(ni * 16 + fr) * 40 + fq * 8];
        acc1[ni] = MF(a, b1, acc1[ni]);
      }
    }
    __syncthreads();
  }
}

template <bool F32OUT>
__global__ __launch_bounds__(256) void gemm_table_k(const float* __restrict__ A, int M,
                                                    const u16* __restrict__ BT,
                                                    const float* __restrict__ bias,
                                                    void* __restrict__ C) {
  __shared__ u16 ldsA[64 * 40], ldsB[64 * 40];
  const int m0 = blockIdx.x * 64, n0 = blockIdx.y * 64;
  const int tid = threadIdx.x;
  f32x4 acc[4] = {};
  gemm_tiles<1, true>(A + (size_t)m0 * 512, M - m0, BT + (size_t)n0 * 512, nullptr,
                      ldsA, ldsB, nullptr, tid, acc, nullptr);
  const int lane = tid & 63, wid = tid >> 6, fr = lane & 15, fq = lane >> 4;
#pragma unroll
  for (int ni = 0; ni < 4; ++ni) {
    int col = n0 + ni * 16 + fr;
    float bv = bias ? bias[col] : 0.f;
#pragma unroll
    for (int r = 0; r < 4; ++r) {
      int row = m0 + wid * 16 + fq * 4 + r;
      if (row < M) {
        float v = acc[ni][r] + bv;
        if constexpr (F32OUT)
          ((float*)C)[(size_t)row * 512 + col] = v;
        else
          ((u16*)C)[(size_t)row * 512 + col] = f2bf(v);
      }
    }
  }
}

// paired: C0 = A@BT0 (+bias0), C1 = A@BT1 (+bias1) — shared A staging
__global__ __launch_bounds__(256) void gemm_table2_k(const float* __restrict__ A, int M,
                                                     const u16* __restrict__ BT0,
                                                     const u16* __restrict__ BT1,
                                                     const float* __restrict__ bias0,
                                                     const float* __restrict__ bias1,
                                                     u16* __restrict__ C0,
                                                     u16* __restrict__ C1) {
  __shared__ u16 ldsA[64 * 40], ldsB0[64 * 40], ldsB1[64 * 40];
  const int m0 = blockIdx.x * 64, n0 = blockIdx.y * 64;
  const int tid = threadIdx.x;
  f32x4 acc0[4] = {}, acc1[4] = {};
  gemm_tiles<2, true>(A + (size_t)m0 * 512, M - m0, BT0 + (size_t)n0 * 512,
                      BT1 + (size_t)n0 * 512, ldsA, ldsB0, ldsB1, tid, acc0, acc1);
  const int lane = tid & 63, wid = tid >> 6, fr = lane & 15, fq = lane >> 4;
#pragma unroll
  for (int ni = 0; ni < 4; ++ni) {
    int col = n0 + ni * 16 + fr;
    float b0 = bias0 ? bias0[col] : 0.f;
    float b1 = bias1 ? bias1[col] : 0.f;
#pragma unroll
    for (int r = 0; r < 4; ++r) {
      int row = m0 + wid * 16 + fq * 4 + r;
      if (row < M) {
        C0[(size_t)row * 512 + col] = f2bf(acc0[ni][r] + b0);
        C1[(size_t)row * 512 + col] = f2bf(acc1[ni][r] + b1);
      }
    }
  }
}

// batched transpose+convert: 14 jobs in one launch (blockIdx.z selects job)
struct CJ { const float* src; u16* dst; };
struct CJobs { CJ j[14]; };
__global__ __launch_bounds__(256) void convTB_k(CJobs jobs) {
  __shared__ float tile[32][33];
  const int z = blockIdx.z;
  const float* src = jobs.j[z].src;
  u16* dst = jobs.j[z].dst;
  const int bi = blockIdx.x, bj = blockIdx.y;
  const int tx = threadIdx.x & 31, ty = threadIdx.x >> 5;
#pragma unroll
  for (int r = 0; r < 4; ++r)
    tile[ty + 8 * r][tx] = src[(size_t)(bj * 32 + ty + 8 * r) * 512 + bi * 32 + tx];
  __syncthreads();
#pragma unroll
  for (int r = 0; r < 4; ++r)
    dst[(size_t)(bi * 32 + ty + 8 * r) * 512 + bj * 32 + tx] = f2bf(tile[tx][ty + 8 * r]);
}

__global__ __launch_bounds__(256) void seqT_k(
    const int* __restrict__ q, const int* __restrict__ c, const int* __restrict__ qd,
    const int* __restrict__ cd, const int* __restrict__ corr,
    int* __restrict__ qT, int* __restrict__ cT, int* __restrict__ qdT,
    int* __restrict__ cdT, int* __restrict__ corrT) {
  const int i = blockIdx.x * 256 + threadIdx.x;
  const int b = i / Sv, t = i % Sv;
  const int o = t * Bv + b;
  qT[o] = q[i]; cT[o] = c[i]; qdT[o] = qd[i]; cdT[o] = cd[i]; corrT[o] = corr[i];
}

__global__ __launch_bounds__(256) void prologue_k(
    const float* __restrict__ h0, u16* __restrict__ hb, unsigned* __restrict__ flags) {
  const int i = blockIdx.x * 256 + threadIdx.x;  // 0 .. 512*512-1
  if (i < 4096) flags[i] = 0u;  // 16mg x 16ns x 16-dword padded slots
  hb[i] = f2bf(h0[i]);
}

// ================= persistent scan kernel =================
// LDS weight layout per matrix (32 cols): 32KB = [kc 0..15][128 slots][8 bf16]
// slot(c,q) = c*4 + (q ^ (c&3) ^ ((c>>2)&3))  (bijective; <=2-way bank alias)
DEV void load_wslice32(const u16* __restrict__ src, u16* dst, int n0, int tid) {
  for (int i = tid; i < 2048; i += 256) {  // 16B pieces
    int q = i & 3, kc = (i >> 2) & 15, c = i >> 6;  // c 0..31
    int slot = c * 4 + (q ^ (c & 3) ^ ((c >> 2) & 3));
    *(bf16x8*)&dst[kc * 1024 + slot * 8] =
        *(const bf16x8*)&src[(size_t)(n0 + c) * 512 + kc * 32 + q * 8];
  }
}

// arrive: drain own sc1 stores -> block rendezvous -> slot store (64B-padded)
DEV void mg_arrive(unsigned* myslot, unsigned phase, int tid) {
  waitv0();
  __syncthreads();
  __builtin_amdgcn_fence(__ATOMIC_RELEASE, "workgroup");
  if (tid == 0)
    __hip_atomic_store(myslot, phase, __ATOMIC_RELAXED, __HIP_MEMORY_SCOPE_AGENT);
}
DEV void mg_wait(unsigned* mgslots, unsigned phase, int tid) {
  if (tid < 16) {
    while (__hip_atomic_load(&mgslots[tid * 16], __ATOMIC_RELAXED,
                             __HIP_MEMORY_SCOPE_AGENT) < phase)
      __builtin_amdgcn_s_sleep(0);
  }
  __syncthreads();
  __builtin_amdgcn_fence(__ATOMIC_ACQUIRE, "workgroup");
}

struct Gath { float xv[4], xs1[4], xs2[4], kbias[4]; int cis[4]; };

__global__ __launch_bounds__(256, 1) void scan_k(
    const u16* __restrict__ Ws1T, const u16* __restrict__ Ws2T, const u16* __restrict__ WkihT,
    const u16* __restrict__ Wp1aT, const u16* __restrict__ Wp2aT,
    const u16* __restrict__ Kcorr, const u16* __restrict__ Kqd, const u16* __restrict__ Kcd,
    const u16* __restrict__ P1c, const u16* __restrict__ P2c,
    const u16* __restrict__ XQS1, const u16* __restrict__ XQS2,
    const u16* __restrict__ XCS1, const u16* __restrict__ XCS2,
    const u16* __restrict__ XQDS1, const u16* __restrict__ XQDS2,
    const u16* __restrict__ XCDS1, const u16* __restrict__ XCDS2,
    const int* __restrict__ qT, const int* __restrict__ cT, const int* __restrict__ qdT,
    const int* __restrict__ cdT, const int* __restrict__ corrT,
    const float* __restrict__ XQ, const float* __restrict__ XC, const float* __restrict__ XQD,
    const float* __restrict__ XCD, const float* __restrict__ h0,
    u16* __restrict__ sdf, u16* __restrict__ hb,
    float* __restrict__ dotpart, unsigned* __restrict__ flags) {
  __shared__ u16 wlds[32768];   // Ws1 (32KB) + Ws2 (32KB), 32-col slices
  __shared__ u16 panel[16384];  // 32KB shared A-panel: [kc 0..15][128 slots][8]
  const int bid = blockIdx.x;
  const int mg = (bid & 7) | ((bid >> 7) << 3);  // 0..15; bid&7 = XCD heuristic
  const int ns = (bid >> 3) & 15;                // 0..15
  const int n0 = ns * 32;
  const int tid = threadIdx.x, lane = tid & 63, w = tid >> 6;
  const int rt = w >> 1, ct = w & 1;             // row-tile / col-tile of wave
  const int fr = lane & 15, fq = lane >> 4;

  load_wslice32(Ws1T, wlds,          n0, tid);
  load_wslice32(Ws2T, wlds + 16384,  n0, tid);

  const int col = n0 + ct * 16 + fr;
  const float kco0 = bf2f(Kcorr[col]), kco1 = bf2f(Kcorr[512 + col]);
  const float p1c0 = bf2f(P1c[col]),   p1c1 = bf2f(P1c[512 + col]);
  const float p2c0 = bf2f(P2c[col]),   p2c1 = bf2f(P2c[512 + col]);

  const int prow = rt * 16 + fr;                 // panel row 0..31
  const int crow0 = mg * 32 + rt * 16 + fq * 4;  // C-layout rows (r=0..3)
  const size_t aoff = (size_t)(mg * 32 + prow) * 512;  // global row base (elems)
  const int slotr = (ct * 16 + fr) * 4 + (fq ^ (fr & 3) ^ ((fr >> 2) & 3));
  const u16* wb = wlds + slotr * 8;
  const int pslot = prow * 4 + (fq ^ (prow & 3) ^ ((prow >> 2) & 3));

  // hoisted read-only weight fragments
  bf16x8 wkf[16], wp1f[16], wp2f[16];
#pragma unroll
  for (int kc = 0; kc < 16; ++kc) {
    wkf[kc]  = *(const bf16x8*)(WkihT + (size_t)col * 512 + kc * 32 + fq * 8);
    wp1f[kc] = *(const bf16x8*)(Wp1aT + (size_t)col * 512 + kc * 32 + fq * 8);
    wp2f[kc] = *(const bf16x8*)(Wp2aT + (size_t)col * 512 + kc * 32 + fq * 8);
  }

  unsigned* myslot  = flags + (mg * 16 + ns) * 16;  // own 64B line
  unsigned* mgslots = flags + mg * 16 * 16;

  float hl[4];
#pragma unroll
  for (int r = 0; r < 4; ++r) hl[r] = h0[(size_t)(crow0 + r) * 512 + col];

  // gather set for step tt: xs/kbias/cis @ index tt, xv @ index tt+1
  auto gather_set = [&](Gath& S, int tt) {
#pragma unroll
    for (int r = 0; r < 4; ++r) {
      const int row = crow0 + r;
      int qi0 = qT[tt * Bv + row],  cc0 = cT[tt * Bv + row];
      int qd0 = qdT[tt * Bv + row], cd0 = cdT[tt * Bv + row];
      int ci  = corrT[tt * Bv + row];
      S.cis[r] = ci;
      S.kbias[r] = (ci ? kco1 : kco0) + bf2f(Kqd[qd0 * 512 + col]) +
                   bf2f(Kcd[cd0 * 512 + col]);
      S.xs1[r] = bf2f(XQS1[(size_t)qi0 * 512 + col]) + bf2f(XCS1[(size_t)cc0 * 512 + col]) +
                 bf2f(XQDS1[(size_t)qd0 * 512 + col]) + bf2f(XCDS1[(size_t)cd0 * 512 + col]);
      S.xs2[r] = bf2f(XQS2[(size_t)qi0 * 512 + col]) + bf2f(XCS2[(size_t)cc0 * 512 + col]) +
                 bf2f(XQDS2[(size_t)qd0 * 512 + col]) + bf2f(XCDS2[(size_t)cd0 * 512 + col]);
      int qi1 = qT[(tt + 1) * Bv + row],  cc1 = cT[(tt + 1) * Bv + row];
      int qd1 = qdT[(tt + 1) * Bv + row], cd1 = cdT[(tt + 1) * Bv + row];
      S.xv[r] = XQ[(size_t)qi1 * 512 + col] + XC[(size_t)cc1 * 512 + col] +
                XQD[(size_t)qd1 * 512 + col] + XCD[(size_t)cd1 * 512 + col];
    }
  };

  auto step_body = [&](int t, Gath& CUR, Gath& NXT) {
    // ---------- phase 1: hb panel (deduped) -> sdf + gamma ----------
    {
      LDU tmp[8];
      __builtin_amdgcn_sched_barrier(0);
#pragma unroll
      for (int j = 0; j < 8; ++j)
        ld16v(&tmp[j].f, hb + aoff + (ct * 8 + j) * 32 + fq * 8);
      waitv0();
#pragma unroll
      for (int j = 0; j < 8; ++j)
        *(bf16x8*)&panel[(ct * 8 + j) * 1024 + pslot * 8] = tmp[j].b;
    }
    __syncthreads();  // panel visible to sibling waves
    f32x4 a1 = {}, a2 = {};
#pragma unroll
    for (int kc = 0; kc < 16; ++kc) {
      bf16x8 a = *(const bf16x8*)&panel[kc * 1024 + pslot * 8];
      a1 = MF(a, *(const bf16x8*)(wb + kc * 1024), a1);
      a2 = MF(a, *(const bf16x8*)(wb + 16384 + kc * 1024), a2);
    }
#pragma unroll
    for (int r = 0; r < 4; ++r)
      st2v(&sdf[(size_t)(crow0 + r) * 512 + col],
           f2bf(sigm(CUR.xs1[r] - a1[r]) * tanh_(CUR.xs2[r] - a2[r])));
    // gamma pass overlaps sdf store acks
    f32x4 ag = {};
#pragma unroll
    for (int kc = 0; kc < 16; ++kc)
      ag = MF(*(const bf16x8*)&panel[kc * 1024 + pslot * 8], wkf[kc], ag);
    float g[4];
#pragma unroll
    for (int r = 0; r < 4; ++r) g[r] = sigm(ag[r] + CUR.kbias[r]);
    mg_arrive(myslot, (unsigned)(2 * t + 1), tid);
    mg_wait(mgslots, (unsigned)(2 * t + 1), tid);

    // ---------- phase 2: sdf panel (deduped) -> pka, h ----------
    {
      LDU tmp[8];
      __builtin_amdgcn_sched_barrier(0);
#pragma unroll
      for (int j = 0; j < 8; ++j)
        ld16v(&tmp[j].f, sdf + aoff + (ct * 8 + j) * 32 + fq * 8);
      waitv0();
#pragma unroll
      for (int j = 0; j < 8; ++j)
        *(bf16x8*)&panel[(ct * 8 + j) * 1024 + pslot * 8] = tmp[j].b;
    }
    __syncthreads();
    f32x4 ap1 = {}, ap2 = {};
#pragma unroll
    for (int kc = 0; kc < 16; ++kc) {
      bf16x8 a = *(const bf16x8*)&panel[kc * 1024 + pslot * 8];
      ap1 = MF(a, wp1f[kc], ap1);
      ap2 = MF(a, wp2f[kc], ap2);
    }
    float dots[4];
#pragma unroll
    for (int r = 0; r < 4; ++r) {
      const int row = crow0 + r;
      float pka = sigm(ap1[r] + (CUR.cis[r] ? p1c1 : p1c0)) *
                  tanh_(ap2[r] + (CUR.cis[r] ? p2c1 : p2c0));
      float hn = g[r] * hl[r] + (1.f - g[r]) * pka;
      hl[r] = hn;
      st2v(&hb[(size_t)row * 512 + col], f2bf(hn));
      dots[r] = CUR.xv[r] * hn;
    }
    mg_arrive(myslot, (unsigned)(2 * t + 2), tid);
    // barrier-2 shadow: dot reduction + dotpart + NEXT gather set (for t+1)
#pragma unroll
    for (int r = 0; r < 4; ++r) {
      float v = dots[r];
      v += __shfl_xor(v, 1);
      v += __shfl_xor(v, 2);
      v += __shfl_xor(v, 4);
      v += __shfl_xor(v, 8);
      if (fr == 0) dotpart[((size_t)t * Bv + crow0 + r) * 32 + ns * 2 + ct] = v;
    }
    if (t + 1 < Sv - 1) gather_set(NXT, t + 1);
    mg_wait(mgslots, (unsigned)(2 * t + 2), tid);
  };

  Gath gA, gB;
  gather_set(gA, 0);
  __syncthreads();  // weight LDS ready

  for (int t = 0; t < Sv - 1; t += 2) {
    step_body(t, gA, gB);
    if (t + 1 < Sv - 1) step_body(t + 1, gB, gA);
  }
}

// ================= finalize =================
__global__ __launch_bounds__(256) void finalize_k(const float* __restrict__ dotpart,
                                                  float* __restrict__ y) {
  const int i = blockIdx.x * 256 + threadIdx.x;  // 0..102399
  const int b = i / Sv, t = i % Sv;
  float v = 0.f;
  if (t < Sv - 1) {
    const float4* p = (const float4*)&dotpart[((size_t)t * Bv + b) * 32];
    float s = 0.f;
#pragma unroll
    for (int k = 0; k < 8; ++k) {
      float4 q = p[k];
      s += q.x + q.y + q.z + q.w;
    }
    v = sigm(s);
  }
  y[i] = v;
}

// ================= host =================
extern "C" void kernel_launch(void* const* d_in, const int* in_sizes, int n_in,
                              void* d_out, int out_size, void* d_ws, size_t ws_size,
                              hipStream_t stream) {
  (void)in_sizes; (void)n_in; (void)out_size; (void)ws_size;
  const int* q_seq    = (const int*)d_in[0];
  const int* c_seq    = (const int*)d_in[1];
  const int* qd_seq   = (const int*)d_in[2];
  const int* cd_seq   = (const int*)d_in[3];
  const int* corr_seq = (const int*)d_in[4];
  const float* E_q    = (const float*)d_in[5];
  const float* E_c    = (const float*)d_in[6];
  const float* E_qd   = (const float*)d_in[7];
  const float* E_cd   = (const float*)d_in[8];
  const float* E_corr = (const float*)d_in[9];
  const float* W_x  = (const float*)d_in[10];
  const float* b_x  = (const float*)d_in[11];
  const float* W_s1 = (const float*)d_in[12];
  const float* b_s1 = (const float*)d_in[13];
  const float* W_s2 = (const float*)d_in[14];
  const float* b_s2 = (const float*)d_in[15];
  const float* W_p1 = (const float*)d_in[16];
  const float* b_p1 = (const float*)d_in[17];
  const float* W_p2 = (const float*)d_in[18];
  const float* b_p2 = (const float*)d_in[19];
  const float* W_ki = (const float*)d_in[20];
  const float* b_ki = (const float*)d_in[21];
  const float* h0   = (const float*)d_in[22];
  float* y = (float*)d_out;

  char* ws = (char*)d_ws;
  size_t off = 0;
  auto alloc = [&](size_t bytes) -> void* {
    void* p = ws + off;
    off += (bytes + 255) & ~(size_t)255;
    return p;
  };
  const size_t WSZ = 512 * 512 * sizeof(u16);
  u16* WxTq  = (u16*)alloc(WSZ);
  u16* WxTc  = (u16*)alloc(WSZ);
  u16* WxTqd = (u16*)alloc(WSZ);
  u16* WxTcd = (u16*)alloc(WSZ);
  u16* Ws1T  = (u16*)alloc(WSZ);
  u16* Ws2T  = (u16*)alloc(WSZ);
  u16* WkihT = (u16*)alloc(WSZ);
  u16* WkiTco = (u16*)alloc(WSZ);
  u16* WkiTqd = (u16*)alloc(WSZ);
  u16* WkiTcd = (u16*)alloc(WSZ);
  u16* Wp1aT = (u16*)alloc(WSZ);
  u16* Wp1hT = (u16*)alloc(WSZ);
  u16* Wp2aT = (u16*)alloc(WSZ);
  u16* Wp2hT = (u16*)alloc(WSZ);
  float* XQf  = (float*)alloc((size_t)10000 * 512 * 4);
  float* XCf  = (float*)alloc((size_t)500 * 512 * 4);
  float* XQDf = (float*)alloc((size_t)101 * 512 * 4);
  float* XCDf = (float*)alloc((size_t)101 * 512 * 4);
  u16* XQS1  = (u16*)alloc((size_t)10000 * 512 * 2);
  u16* XQS2  = (u16*)alloc((size_t)10000 * 512 * 2);
  u16* XCS1  = (u16*)alloc((size_t)500 * 512 * 2);
  u16* XCS2  = (u16*)alloc((size_t)500 * 512 * 2);
  u16* XQDS1 = (u16*)alloc((size_t)101 * 512 * 2);
  u16* XQDS2 = (u16*)alloc((size_t)101 * 512 * 2);
  u16* XCDS1 = (u16*)alloc((size_t)101 * 512 * 2);
  u16* XCDS2 = (u16*)alloc((size_t)101 * 512 * 2);
  u16* Kcorr = (u16*)alloc((size_t)2 * 512 * 2);
  u16* Kqd   = (u16*)alloc((size_t)101 * 512 * 2);
  u16* Kcd   = (u16*)alloc((size_t)101 * 512 * 2);
  u16* P1c   = (u16*)alloc((size_t)2 * 512 * 2);
  u16* P2c   = (u16*)alloc((size_t)2 * 512 * 2);
  u16* sdf   = (u16*)alloc((size_t)512 * 512 * 2);
  u16* hb    = (u16*)alloc((size_t)512 * 512 * 2);
  float* dotpart = (float*)alloc((size_t)199 * 512 * 32 * 4);
  int* qT    = (int*)alloc((size_t)Sv * Bv * 4);
  int* cT    = (int*)alloc((size_t)Sv * Bv * 4);
  int* qdT   = (int*)alloc((size_t)Sv * Bv * 4);
  int* cdT   = (int*)alloc((size_t)Sv * Bv * 4);
  int* corrT = (int*)alloc((size_t)Sv * Bv * 4);
  unsigned* flags = (unsigned*)alloc(8192 * 4);  // 4096 used

  dim3 blk(256);
  // batched weight transposes (1 launch)
  {
    CJobs jobs;
    const float* srcs[14] = {W_x, W_x + 512 * 512, W_x + 2 * 512 * 512, W_x + 3 * 512 * 512,
                             W_s1, W_s2, W_ki, W_ki + 512 * 512, W_ki + 2 * 512 * 512,
                             W_ki + 3 * 512 * 512, W_p1, W_p1 + 512 * 512,
                             W_p2, W_p2 + 512 * 512};
    u16* dsts[14] = {WxTq, WxTc, WxTqd, WxTcd, Ws1T, Ws2T, WkihT, WkiTco, WkiTqd,
                     WkiTcd, Wp1aT, Wp1hT, Wp2aT, Wp2hT};
    for (int i = 0; i < 14; ++i) { jobs.j[i].src = srcs[i]; jobs.j[i].dst = dsts[i]; }
    convTB_k<<<dim3(16, 16, 14), blk, 0, stream>>>(jobs);
  }

  gemm_table_k<true><<<dim3(157, 8), blk, 0, stream>>>(E_q, 10000, WxTq, nullptr, XQf);
  gemm_table_k<true><<<dim3(8, 8), blk, 0, stream>>>(E_c, 500, WxTc, b_x, XCf);
  gemm_table_k<true><<<dim3(2, 8), blk, 0, stream>>>(E_qd, 101, WxTqd, nullptr, XQDf);
  gemm_table_k<true><<<dim3(2, 8), blk, 0, stream>>>(E_cd, 101, WxTcd, nullptr, XCDf);

  gemm_table2_k<<<dim3(157, 8), blk, 0, stream>>>(XQf, 10000, Ws1T, Ws2T,
                                                  nullptr, nullptr, XQS1, XQS2);
  gemm_table2_k<<<dim3(8, 8), blk, 0, stream>>>(XCf, 500, Ws1T, Ws2T,
                                                b_s1, b_s2, XCS1, XCS2);
  gemm_table2_k<<<dim3(2, 8), blk, 0, stream>>>(XQDf, 101, Ws1T, Ws2T,
                                                nullptr, nullptr, XQDS1, XQDS2);
  gemm_table2_k<<<dim3(2, 8), blk, 0, stream>>>(XCDf, 101, Ws1T, Ws2T,
                                                nullptr, nullptr, XCDS1, XCDS2);

  gemm_table_k<false><<<dim3(1, 8), blk, 0, stream>>>(E_corr, 2, WkiTco, b_ki, Kcorr);
  gemm_table_k<false><<<dim3(2, 8), blk, 0, stream>>>(E_qd, 101, WkiTqd, nullptr, Kqd);
  gemm_table_k<false><<<dim3(2, 8), blk, 0, stream>>>(E_cd, 101, WkiTcd, nullptr, Kcd);
  gemm_table_k<false><<<dim3(1, 8), blk, 0, stream>>>(E_corr, 2, Wp1hT, b_p1, P1c);
  gemm_table_k<false><<<dim3(1, 8), blk, 0, stream>>>(E_corr, 2, Wp2hT, b_p2, P2c);

  seqT_k<<<dim3(400), blk, 0, stream>>>(q_seq, c_seq, qd_seq, cd_seq, corr_seq,
                                        qT, cT, qdT, cdT, corrT);
  prologue_k<<<dim3(1024), blk, 0, stream>>>(h0, hb, flags);

  // persistent scan (cooperative for guaranteed co-residency; plain fallback)
  {
    const u16 *a0 = Ws1T, *a1 = Ws2T, *a2 = WkihT, *a3 = Wp1aT, *a4 = Wp2aT;
    const u16 *a5 = Kcorr, *a6 = Kqd, *a7 = Kcd, *a8 = P1c, *a9 = P2c;
    const u16 *a10 = XQS1, *a11 = XQS2, *a12 = XCS1, *a13 = XCS2;
    const u16 *a14 = XQDS1, *a15 = XQDS2, *a16 = XCDS1, *a17 = XCDS2;
    const int *a18 = qT, *a19 = cT, *a20 = qdT, *a21 = cdT, *a22 = corrT;
    const float *a23 = XQf, *a24 = XCf, *a25 = XQDf, *a26 = XCDf, *a27 = h0;
    u16 *a28 = sdf, *a29 = hb;
    float* a30 = dotpart;
    unsigned* a31 = flags;
    void* args[] = {&a0, &a1, &a2, &a3, &a4, &a5, &a6, &a7, &a8, &a9,
                    &a10, &a11, &a12, &a13, &a14, &a15, &a16, &a17,
                    &a18, &a19, &a20, &a21, &a22, &a23, &a24, &a25, &a26, &a27,
                    &a28, &a29, &a30, &a31};
    hipError_t e = hipLaunchCooperativeKernel((void*)scan_k, dim3(256), dim3(256),
                                              args, 0, stream);
    if (e != hipSuccess) {
      scan_k<<<dim3(256), dim3(256), 0, stream>>>(Ws1T, Ws2T, WkihT, Wp1aT, Wp2aT,
                                                  Kcorr, Kqd, Kcd, P1c, P2c,
                                                  XQS1, XQS2, XCS1, XCS2,
                                                  XQDS1, XQDS2, XCDS1, XCDS2,
                                                  qT, cT, qdT, cdT, corrT,
                                                  XQf, XCf, XQDf, XCDf, h0,
                                                  sdf, hb, dotpart, flags);
    }
  }

  finalize_k<<<dim3(400), blk, 0, stream>>>(dotpart, y);
}

// Round 16
// 2028.087 us; speedup vs baseline: 1.1842x; 1.1842x over previous
//
#include <hip/hip_runtime.h>

// DIMKT round 15: R13 revert (proven 1805us scan) + P1 drain-overlap only.
//   P1: a1/a2 MFMAs -> issue sdf stores -> gamma MFMAs + g (acks drain under
//   them) -> arrive. Gathers stay in R13's balanced shadows (xv+xs under
//   barrier-1, kbias+dots under barrier-2). Protocol: sc1 IF$ data plane,
//   agent-atomic 64B-padded slot barrier, LDS panel dedup, batched precompute.

typedef unsigned short u16;
using f32x4 = __attribute__((ext_vector_type(4))) float;
using bf16x8 = __attribute__((ext_vector_type(8))) short;

#define DEV static __device__ __forceinline__

#define Bv 512
#define Sv 200

DEV u16 f2bf(float f) {
  unsigned int u = __float_as_uint(f);
  unsigned int r = (u + 0x7fffu + ((u >> 16) & 1u)) >> 16;
  return (u16)r;
}
DEV float bf2f(u16 h) { return __uint_as_float(((unsigned int)h) << 16); }
DEV float sigm(float x) { return 1.0f / (1.0f + __expf(-x)); }
DEV float tanh_(float x) {
  x = fmaxf(fminf(x, 15.f), -15.f);
  float e = __expf(2.0f * x);
  return (e - 1.0f) / (e + 1.0f);
}
DEV f32x4 MF(bf16x8 a, bf16x8 b, f32x4 c) {
  return __builtin_amdgcn_mfma_f32_16x16x32_bf16(a, b, c, 0, 0, 0);
}

// ---- pipelined agent-scope (sc1) data plane (R7..R13-proven) ----
union LDU { f32x4 f; bf16x8 b; };
DEV void ld16v(f32x4* d, const u16* p) {  // issue; NO wait
  asm volatile("global_load_dwordx4 %0, %1, off sc1" : "=v"(*d) : "v"(p));
}
DEV void st2v(u16* p, u16 v) {  // write-through to coherence point
  unsigned w = v;
  asm volatile("global_store_short %0, %1, off sc1" : : "v"(p), "v"(w) : "memory");
}
DEV void waitv0() {
  asm volatile("s_waitcnt vmcnt(0)" ::: "memory");
  __builtin_amdgcn_sched_barrier(0);  // rule #18
}

// ================= precompute machinery (round-0, verified) =================
template <int NB, bool AF32>
DEV void gemm_tiles(const void* __restrict__ Aptr, int mvalid,
                    const u16* __restrict__ BT0, const u16* __restrict__ BT1,
                    u16* ldsA, u16* ldsB0, u16* ldsB1, int tid,
                    f32x4* acc0, f32x4* acc1) {
  const int lane = tid & 63, wid = tid >> 6;
  const int fr = lane & 15, fq = lane >> 4;
  const int srow = tid >> 2, sseg = tid & 3;

  for (int kt = 0; kt < 16; ++kt) {
    const int k0 = kt * 32;
    {
      bf16x8 pack;
      if constexpr (AF32) {
        if (srow < mvalid) {
          const float4* ap = (const float4*)((const float*)Aptr + (size_t)srow * 512 + k0 + sseg * 8);
          float4 v0 = ap[0], v1 = ap[1];
          pack[0] = (short)f2bf(v0.x); pack[1] = (short)f2bf(v0.y);
          pack[2] = (short)f2bf(v0.z); pack[3] = (short)f2bf(v0.w);
          pack[4] = (short)f2bf(v1.x); pack[5] = (short)f2bf(v1.y);
          pack[6] = (short)f2bf(v1.z); pack[7] = (short)f2bf(v1.w);
        } else {
          for (int j = 0; j < 8; ++j) pack[j] = 0;
        }
      } else {
        pack = *(const bf16x8*)((const u16*)Aptr + (size_t)srow * 512 + k0 + sseg * 8);
      }
      *(bf16x8*)&ldsA[srow * 40 + sseg * 8] = pack;
      *(bf16x8*)&ldsB0[srow * 40 + sseg * 8] =
          *(const bf16x8*)(BT0 + (size_t)srow * 512 + k0 + sseg * 8);
      if constexpr (NB == 2)
        *(bf16x8*)&ldsB1[srow * 40 + sseg * 8] =
            *(const bf16x8*)(BT1 + (size_t)srow * 512 + k0 + sseg * 8);
    }
    __syncthreads();
    bf16x8 a = *(const bf16x8*)&ldsA[(wid * 16 + fr) * 40 + fq * 8];
#pragma unroll
    for (int ni = 0; ni < 4; ++ni) {
      bf16x8 b0 = *(const bf16x8*)&ldsB0[(ni * 16 + fr) * 40 + fq * 8];
      acc0[ni] = MF(a, b0, acc0[ni]);
      if constexpr (NB == 2) {
        bf16x8 b1 = *(const bf16x8*)&ldsB1[(ni * 16 + fr) * 40 + fq * 8];
        acc1[ni] = MF(a, b1, acc1[ni]);
      }
    }
    __syncthreads();
  }
}

template <bool F32OUT>
__global__ __launch_bounds__(256) void gemm_table_k(const float* __restrict__ A, int M,
                                                    const u16* __restrict__ BT,
                                                    const float* __restrict__ bias,
                                                    void* __restrict__ C) {
  __shared__ u16 ldsA[64 * 40], ldsB[64 * 40];
  const int m0 = blockIdx.x * 64, n0 = blockIdx.y * 64;
  const int tid = threadIdx.x;
  f32x4 acc[4] = {};
  gemm_tiles<1, true>(A + (size_t)m0 * 512, M - m0, BT + (size_t)n0 * 512, nullptr,
                      ldsA, ldsB, nullptr, tid, acc, nullptr);
  const int lane = tid & 63, wid = tid >> 6, fr = lane & 15, fq = lane >> 4;
#pragma unroll
  for (int ni = 0; ni < 4; ++ni) {
    int col = n0 + ni * 16 + fr;
    float bv = bias ? bias[col] : 0.f;
#pragma unroll
    for (int r = 0; r < 4; ++r) {
      int row = m0 + wid * 16 + fq * 4 + r;
      if (row < M) {
        float v = acc[ni][r] + bv;
        if constexpr (F32OUT)
          ((float*)C)[(size_t)row * 512 + col] = v;
        else
          ((u16*)C)[(size_t)row * 512 + col] = f2bf(v);
      }
    }
  }
}

// paired: C0 = A@BT0 (+bias0), C1 = A@BT1 (+bias1) — shared A staging
__global__ __launch_bounds__(256) void gemm_table2_k(const float* __restrict__ A, int M,
                                                     const u16* __restrict__ BT0,
                                                     const u16* __restrict__ BT1,
                                                     const float* __restrict__ bias0,
                                                     const float* __restrict__ bias1,
                                                     u16* __restrict__ C0,
                                                     u16* __restrict__ C1) {
  __shared__ u16 ldsA[64 * 40], ldsB0[64 * 40], ldsB1[64 * 40];
  const int m0 = blockIdx.x * 64, n0 = blockIdx.y * 64;
  const int tid = threadIdx.x;
  f32x4 acc0[4] = {}, acc1[4] = {};
  gemm_tiles<2, true>(A + (size_t)m0 * 512, M - m0, BT0 + (size_t)n0 * 512,
                      BT1 + (size_t)n0 * 512, ldsA, ldsB0, ldsB1, tid, acc0, acc1);
  const int lane = tid & 63, wid = tid >> 6, fr = lane & 15, fq = lane >> 4;
#pragma unroll
  for (int ni = 0; ni < 4; ++ni) {
    int col = n0 + ni * 16 + fr;
    float b0 = bias0 ? bias0[col] : 0.f;
    float b1 = bias1 ? bias1[col] : 0.f;
#pragma unroll
    for (int r = 0; r < 4; ++r) {
      int row = m0 + wid * 16 + fq * 4 + r;
      if (row < M) {
        C0[(size_t)row * 512 + col] = f2bf(acc0[ni][r] + b0);
        C1[(size_t)row * 512 + col] = f2bf(acc1[ni][r] + b1);
      }
    }
  }
}

// batched transpose+convert: 14 jobs in one launch (blockIdx.z selects job)
struct CJ { const float* src; u16* dst; };
struct CJobs { CJ j[14]; };
__global__ __launch_bounds__(256) void convTB_k(CJobs jobs) {
  __shared__ float tile[32][33];
  const int z = blockIdx.z;
  const float* src = jobs.j[z].src;
  u16* dst = jobs.j[z].dst;
  const int bi = blockIdx.x, bj = blockIdx.y;
  const int tx = threadIdx.x & 31, ty = threadIdx.x >> 5;
#pragma unroll
  for (int r = 0; r < 4; ++r)
    tile[ty + 8 * r][tx] = src[(size_t)(bj * 32 + ty + 8 * r) * 512 + bi * 32 + tx];
  __syncthreads();
#pragma unroll
  for (int r = 0; r < 4; ++r)
    dst[(size_t)(bi * 32 + ty + 8 * r) * 512 + bj * 32 + tx] = f2bf(tile[tx][ty + 8 * r]);
}

__global__ __launch_bounds__(256) void seqT_k(
    const int* __restrict__ q, const int* __restrict__ c, const int* __restrict__ qd,
    const int* __restrict__ cd, const int* __restrict__ corr,
    int* __restrict__ qT, int* __restrict__ cT, int* __restrict__ qdT,
    int* __restrict__ cdT, int* __restrict__ corrT) {
  const int i = blockIdx.x * 256 + threadIdx.x;
  const int b = i / Sv, t = i % Sv;
  const int o = t * Bv + b;
  qT[o] = q[i]; cT[o] = c[i]; qdT[o] = qd[i]; cdT[o] = cd[i]; corrT[o] = corr[i];
}

__global__ __launch_bounds__(256) void prologue_k(
    const float* __restrict__ h0, u16* __restrict__ hb, unsigned* __restrict__ flags) {
  const int i = blockIdx.x * 256 + threadIdx.x;  // 0 .. 512*512-1
  if (i < 4096) flags[i] = 0u;  // 16mg x 16ns x 16-dword padded slots
  hb[i] = f2bf(h0[i]);
}

// ================= persistent scan kernel =================
// LDS weight layout per matrix (32 cols): 32KB = [kc 0..15][128 slots][8 bf16]
// slot(c,q) = c*4 + (q ^ (c&3) ^ ((c>>2)&3))  (bijective; <=2-way bank alias)
DEV void load_wslice32(const u16* __restrict__ src, u16* dst, int n0, int tid) {
  for (int i = tid; i < 2048; i += 256) {  // 16B pieces
    int q = i & 3, kc = (i >> 2) & 15, c = i >> 6;  // c 0..31
    int slot = c * 4 + (q ^ (c & 3) ^ ((c >> 2) & 3));
    *(bf16x8*)&dst[kc * 1024 + slot * 8] =
        *(const bf16x8*)&src[(size_t)(n0 + c) * 512 + kc * 32 + q * 8];
  }
}

// arrive: drain own sc1 stores -> block rendezvous -> slot store (64B-padded)
DEV void mg_arrive(unsigned* myslot, unsigned phase, int tid) {
  waitv0();
  __syncthreads();
  __builtin_amdgcn_fence(__ATOMIC_RELEASE, "workgroup");
  if (tid == 0)
    __hip_atomic_store(myslot, phase, __ATOMIC_RELAXED, __HIP_MEMORY_SCOPE_AGENT);
}
DEV void mg_wait(unsigned* mgslots, unsigned phase, int tid) {
  if (tid < 16) {
    while (__hip_atomic_load(&mgslots[tid * 16], __ATOMIC_RELAXED,
                             __HIP_MEMORY_SCOPE_AGENT) < phase)
      __builtin_amdgcn_s_sleep(0);
  }
  __syncthreads();
  __builtin_amdgcn_fence(__ATOMIC_ACQUIRE, "workgroup");
}

__global__ __launch_bounds__(256, 1) void scan_k(
    const u16* __restrict__ Ws1T, const u16* __restrict__ Ws2T, const u16* __restrict__ WkihT,
    const u16* __restrict__ Wp1aT, const u16* __restrict__ Wp2aT,
    const u16* __restrict__ Kcorr, const u16* __restrict__ Kqd, const u16* __restrict__ Kcd,
    const u16* __restrict__ P1c, const u16* __restrict__ P2c,
    const u16* __restrict__ XQS1, const u16* __restrict__ XQS2,
    const u16* __restrict__ XCS1, const u16* __restrict__ XCS2,
    const u16* __restrict__ XQDS1, const u16* __restrict__ XQDS2,
    const u16* __restrict__ XCDS1, const u16* __restrict__ XCDS2,
    const int* __restrict__ qT, const int* __restrict__ cT, const int* __restrict__ qdT,
    const int* __restrict__ cdT, const int* __restrict__ corrT,
    const float* __restrict__ XQ, const float* __restrict__ XC, const float* __restrict__ XQD,
    const float* __restrict__ XCD, const float* __restrict__ h0,
    u16* __restrict__ sdf, u16* __restrict__ hb,
    float* __restrict__ dotpart, unsigned* __restrict__ flags) {
  __shared__ u16 wlds[32768];   // Ws1 (32KB) + Ws2 (32KB), 32-col slices
  __shared__ u16 panel[16384];  // 32KB shared A-panel: [kc 0..15][128 slots][8]
  const int bid = blockIdx.x;
  const int mg = (bid & 7) | ((bid >> 7) << 3);  // 0..15; bid&7 = XCD heuristic
  const int ns = (bid >> 3) & 15;                // 0..15
  const int n0 = ns * 32;
  const int tid = threadIdx.x, lane = tid & 63, w = tid >> 6;
  const int rt = w >> 1, ct = w & 1;             // row-tile / col-tile of wave
  const int fr = lane & 15, fq = lane >> 4;

  load_wslice32(Ws1T, wlds,          n0, tid);
  load_wslice32(Ws2T, wlds + 16384,  n0, tid);

  const int col = n0 + ct * 16 + fr;
  const float kco0 = bf2f(Kcorr[col]), kco1 = bf2f(Kcorr[512 + col]);
  const float p1c0 = bf2f(P1c[col]),   p1c1 = bf2f(P1c[512 + col]);
  const float p2c0 = bf2f(P2c[col]),   p2c1 = bf2f(P2c[512 + col]);

  const int prow = rt * 16 + fr;                 // panel row 0..31
  const int crow0 = mg * 32 + rt * 16 + fq * 4;  // C-layout rows (r=0..3)
  const size_t aoff = (size_t)(mg * 32 + prow) * 512;  // global row base (elems)
  const int slotr = (ct * 16 + fr) * 4 + (fq ^ (fr & 3) ^ ((fr >> 2) & 3));
  const u16* wb = wlds + slotr * 8;
  // panel slot for this lane's (row, fq-segment); same formula for write+read
  const int pslot = prow * 4 + (fq ^ (prow & 3) ^ ((prow >> 2) & 3));

  // hoisted read-only weight fragments (kernel-boundary coherent plain loads)
  bf16x8 wkf[16], wp1f[16], wp2f[16];
#pragma unroll
  for (int kc = 0; kc < 16; ++kc) {
    wkf[kc]  = *(const bf16x8*)(WkihT + (size_t)col * 512 + kc * 32 + fq * 8);
    wp1f[kc] = *(const bf16x8*)(Wp1aT + (size_t)col * 512 + kc * 32 + fq * 8);
    wp2f[kc] = *(const bf16x8*)(Wp2aT + (size_t)col * 512 + kc * 32 + fq * 8);
  }

  unsigned* myslot  = flags + (mg * 16 + ns) * 16;  // own 64B line
  unsigned* mgslots = flags + mg * 16 * 16;

  float hl[4];
#pragma unroll
  for (int r = 0; r < 4; ++r) hl[r] = h0[(size_t)(crow0 + r) * 512 + col];

  // step-0 gathers: xs (t=0) and kbias (t=0)
  float xs1[4], xs2[4], kbias[4];
  int cis[4];
#pragma unroll
  for (int r = 0; r < 4; ++r) {
    const int row = crow0 + r;
    int qi = qT[row], cci = cT[row], qdi = qdT[row], cdi = cdT[row];
    int ci = corrT[row];
    xs1[r] = bf2f(XQS1[(size_t)qi * 512 + col]) + bf2f(XCS1[(size_t)cci * 512 + col]) +
             bf2f(XQDS1[(size_t)qdi * 512 + col]) + bf2f(XCDS1[(size_t)cdi * 512 + col]);
    xs2[r] = bf2f(XQS2[(size_t)qi * 512 + col]) + bf2f(XCS2[(size_t)cci * 512 + col]) +
             bf2f(XQDS2[(size_t)qdi * 512 + col]) + bf2f(XCDS2[(size_t)cdi * 512 + col]);
    cis[r] = ci;
    kbias[r] = (ci ? kco1 : kco0) + bf2f(Kqd[qdi * 512 + col]) + bf2f(Kcd[cdi * 512 + col]);
  }
  __syncthreads();

  for (int t = 0; t < Sv - 1; ++t) {
    // ---------- phase 1: hb panel (deduped: each wave loads 8 chunks) ----------
    {
      LDU tmp[8];
      __builtin_amdgcn_sched_barrier(0);
#pragma unroll
      for (int j = 0; j < 8; ++j) {
        const int kc = ct * 8 + j;
        ld16v(&tmp[j].f, hb + aoff + kc * 32 + fq * 8);
      }
      waitv0();
#pragma unroll
      for (int j = 0; j < 8; ++j) {
        const int kc = ct * 8 + j;
        *(bf16x8*)&panel[kc * 1024 + pslot * 8] = tmp[j].b;
      }
    }
    __syncthreads();  // panel writes visible to sibling waves
    // a1/a2 first -> sdf stores issue early; gamma MFMAs overlap the drain
    f32x4 a1 = {}, a2 = {};
#pragma unroll
    for (int kc = 0; kc < 16; ++kc) {
      bf16x8 a = *(const bf16x8*)&panel[kc * 1024 + pslot * 8];
      a1 = MF(a, *(const bf16x8*)(wb + kc * 1024), a1);
      a2 = MF(a, *(const bf16x8*)(wb + 16384 + kc * 1024), a2);
    }
#pragma unroll
    for (int r = 0; r < 4; ++r)
      st2v(&sdf[(size_t)(crow0 + r) * 512 + col],
           f2bf(sigm(xs1[r] - a1[r]) * tanh_(xs2[r] - a2[r])));
    f32x4 ag = {};
#pragma unroll
    for (int kc = 0; kc < 16; ++kc)
      ag = MF(*(const bf16x8*)&panel[kc * 1024 + pslot * 8], wkf[kc], ag);
    float g[4];
#pragma unroll
    for (int r = 0; r < 4; ++r) g[r] = sigm(ag[r] + kbias[r]);
    mg_arrive(myslot, (unsigned)(2 * t + 1), tid);
    // barrier-1 shadow: xv gathers (t+1) + xs gathers (t+1, same indices)
    float xv[4];
#pragma unroll
    for (int r = 0; r < 4; ++r) {
      const int row = crow0 + r;
      int qi   = qT[(t + 1) * Bv + row];
      int cci  = cT[(t + 1) * Bv + row];
      int qdi2 = qdT[(t + 1) * Bv + row];
      int cdi2 = cdT[(t + 1) * Bv + row];
      xv[r] = XQ[(size_t)qi * 512 + col] + XC[(size_t)cci * 512 + col] +
              XQD[(size_t)qdi2 * 512 + col] + XCD[(size_t)cdi2 * 512 + col];
      xs1[r] = bf2f(XQS1[(size_t)qi * 512 + col]) + bf2f(XCS1[(size_t)cci * 512 + col]) +
               bf2f(XQDS1[(size_t)qdi2 * 512 + col]) + bf2f(XCDS1[(size_t)cdi2 * 512 + col]);
      xs2[r] = bf2f(XQS2[(size_t)qi * 512 + col]) + bf2f(XCS2[(size_t)cci * 512 + col]) +
               bf2f(XQDS2[(size_t)qdi2 * 512 + col]) + bf2f(XCDS2[(size_t)cdi2 * 512 + col]);
    }
    mg_wait(mgslots, (unsigned)(2 * t + 1), tid);

    // ---------- phase 2: sdf panel (deduped) -> pka, h ----------
    {
      LDU tmp[8];
      __builtin_amdgcn_sched_barrier(0);
#pragma unroll
      for (int j = 0; j < 8; ++j) {
        const int kc = ct * 8 + j;
        ld16v(&tmp[j].f, sdf + aoff + kc * 32 + fq * 8);
      }
      waitv0();
#pragma unroll
      for (int j = 0; j < 8; ++j) {
        const int kc = ct * 8 + j;
        *(bf16x8*)&panel[kc * 1024 + pslot * 8] = tmp[j].b;
      }
    }
    __syncthreads();
    f32x4 ap1 = {}, ap2 = {};
#pragma unroll
    for (int kc = 0; kc < 16; ++kc) {
      bf16x8 a = *(const bf16x8*)&panel[kc * 1024 + pslot * 8];
      ap1 = MF(a, wp1f[kc], ap1);
      ap2 = MF(a, wp2f[kc], ap2);
    }
    float dots[4];
#pragma unroll
    for (int r = 0; r < 4; ++r) {
      const int row = crow0 + r;
      float pka = sigm(ap1[r] + (cis[r] ? p1c1 : p1c0)) *
                  tanh_(ap2[r] + (cis[r] ? p2c1 : p2c0));
      float hn = g[r] * hl[r] + (1.f - g[r]) * pka;
      hl[r] = hn;
      st2v(&hb[(size_t)row * 512 + col], f2bf(hn));
      dots[r] = xv[r] * hn;
    }
    mg_arrive(myslot, (unsigned)(2 * t + 2), tid);
    // barrier-2 shadow: dot reduction + dotpart store + kbias(t+1)
#pragma unroll
    for (int r = 0; r < 4; ++r) {
      float v = dots[r];
      v += __shfl_xor(v, 1);
      v += __shfl_xor(v, 2);
      v += __shfl_xor(v, 4);
      v += __shfl_xor(v, 8);
      if (fr == 0) dotpart[((size_t)t * Bv + crow0 + r) * 32 + ns * 2 + ct] = v;
    }
    if (t < Sv - 2) {
#pragma unroll
      for (int r = 0; r < 4; ++r) {
        const int row = crow0 + r;
        int ci = corrT[(t + 1) * Bv + row];
        int qdi = qdT[(t + 1) * Bv + row];
        int cdi = cdT[(t + 1) * Bv + row];
        cis[r] = ci;
        kbias[r] = (ci ? kco1 : kco0) + bf2f(Kqd[qdi * 512 + col]) +
                   bf2f(Kcd[cdi * 512 + col]);
      }
    }
    mg_wait(mgslots, (unsigned)(2 * t + 2), tid);
  }
}

// ================= finalize =================
__global__ __launch_bounds__(256) void finalize_k(const float* __restrict__ dotpart,
                                                  float* __restrict__ y) {
  const int i = blockIdx.x * 256 + threadIdx.x;  // 0..102399
  const int b = i / Sv, t = i % Sv;
  float v = 0.f;
  if (t < Sv - 1) {
    const float4* p = (const float4*)&dotpart[((size_t)t * Bv + b) * 32];
    float s = 0.f;
#pragma unroll
    for (int k = 0; k < 8; ++k) {
      float4 q = p[k];
      s += q.x + q.y + q.z + q.w;
    }
    v = sigm(s);
  }
  y[i] = v;
}

// ================= host =================
extern "C" void kernel_launch(void* const* d_in, const int* in_sizes, int n_in,
                              void* d_out, int out_size, void* d_ws, size_t ws_size,
                              hipStream_t stream) {
  (void)in_sizes; (void)n_in; (void)out_size; (void)ws_size;
  const int* q_seq    = (const int*)d_in[0];
  const int* c_seq    = (const int*)d_in[1];
  const int* qd_seq   = (const int*)d_in[2];
  const int* cd_seq   = (const int*)d_in[3];
  const int* corr_seq = (const int*)d_in[4];
  const float* E_q    = (const float*)d_in[5];
  const float* E_c    = (const float*)d_in[6];
  const float* E_qd   = (const float*)d_in[7];
  const float* E_cd   = (const float*)d_in[8];
  const float* E_corr = (const float*)d_in[9];
  const float* W_x  = (const float*)d_in[10];
  const float* b_x  = (const float*)d_in[11];
  const float* W_s1 = (const float*)d_in[12];
  const float* b_s1 = (const float*)d_in[13];
  const float* W_s2 = (const float*)d_in[14];
  const float* b_s2 = (const float*)d_in[15];
  const float* W_p1 = (const float*)d_in[16];
  const float* b_p1 = (const float*)d_in[17];
  const float* W_p2 = (const float*)d_in[18];
  const float* b_p2 = (const float*)d_in[19];
  const float* W_ki = (const float*)d_in[20];
  const float* b_ki = (const float*)d_in[21];
  const float* h0   = (const float*)d_in[22];
  float* y = (float*)d_out;

  char* ws = (char*)d_ws;
  size_t off = 0;
  auto alloc = [&](size_t bytes) -> void* {
    void* p = ws + off;
    off += (bytes + 255) & ~(size_t)255;
    return p;
  };
  const size_t WSZ = 512 * 512 * sizeof(u16);
  u16* WxTq  = (u16*)alloc(WSZ);
  u16* WxTc  = (u16*)alloc(WSZ);
  u16* WxTqd = (u16*)alloc(WSZ);
  u16* WxTcd = (u16*)alloc(WSZ);
  u16* Ws1T  = (u16*)alloc(WSZ);
  u16* Ws2T  = (u16*)alloc(WSZ);
  u16* WkihT = (u16*)alloc(WSZ);
  u16* WkiTco = (u16*)alloc(WSZ);
  u16* WkiTqd = (u16*)alloc(WSZ);
  u16* WkiTcd = (u16*)alloc(WSZ);
  u16* Wp1aT = (u16*)alloc(WSZ);
  u16* Wp1hT = (u16*)alloc(WSZ);
  u16* Wp2aT = (u16*)alloc(WSZ);
  u16* Wp2hT = (u16*)alloc(WSZ);
  float* XQf  = (float*)alloc((size_t)10000 * 512 * 4);
  float* XCf  = (float*)alloc((size_t)500 * 512 * 4);
  float* XQDf = (float*)alloc((size_t)101 * 512 * 4);
  float* XCDf = (float*)alloc((size_t)101 * 512 * 4);
  u16* XQS1  = (u16*)alloc((size_t)10000 * 512 * 2);
  u16* XQS2  = (u16*)alloc((size_t)10000 * 512 * 2);
  u16* XCS1  = (u16*)alloc((size_t)500 * 512 * 2);
  u16* XCS2  = (u16*)alloc((size_t)500 * 512 * 2);
  u16* XQDS1 = (u16*)alloc((size_t)101 * 512 * 2);
  u16* XQDS2 = (u16*)alloc((size_t)101 * 512 * 2);
  u16* XCDS1 = (u16*)alloc((size_t)101 * 512 * 2);
  u16* XCDS2 = (u16*)alloc((size_t)101 * 512 * 2);
  u16* Kcorr = (u16*)alloc((size_t)2 * 512 * 2);
  u16* Kqd   = (u16*)alloc((size_t)101 * 512 * 2);
  u16* Kcd   = (u16*)alloc((size_t)101 * 512 * 2);
  u16* P1c   = (u16*)alloc((size_t)2 * 512 * 2);
  u16* P2c   = (u16*)alloc((size_t)2 * 512 * 2);
  u16* sdf   = (u16*)alloc((size_t)512 * 512 * 2);
  u16* hb    = (u16*)alloc((size_t)512 * 512 * 2);
  float* dotpart = (float*)alloc((size_t)199 * 512 * 32 * 4);
  int* qT    = (int*)alloc((size_t)Sv * Bv * 4);
  int* cT    = (int*)alloc((size_t)Sv * Bv * 4);
  int* qdT   = (int*)alloc((size_t)Sv * Bv * 4);
  int* cdT   = (int*)alloc((size_t)Sv * Bv * 4);
  int* corrT = (int*)alloc((size_t)Sv * Bv * 4);
  unsigned* flags = (unsigned*)alloc(8192 * 4);  // 4096 used

  dim3 blk(256);
  // batched weight transposes (1 launch)
  {
    CJobs jobs;
    const float* srcs[14] = {W_x, W_x + 512 * 512, W_x + 2 * 512 * 512, W_x + 3 * 512 * 512,
                             W_s1, W_s2, W_ki, W_ki + 512 * 512, W_ki + 2 * 512 * 512,
                             W_ki + 3 * 512 * 512, W_p1, W_p1 + 512 * 512,
                             W_p2, W_p2 + 512 * 512};
    u16* dsts[14] = {WxTq, WxTc, WxTqd, WxTcd, Ws1T, Ws2T, WkihT, WkiTco, WkiTqd,
                     WkiTcd, Wp1aT, Wp1hT, Wp2aT, Wp2hT};
    for (int i = 0; i < 14; ++i) { jobs.j[i].src = srcs[i]; jobs.j[i].dst = dsts[i]; }
    convTB_k<<<dim3(16, 16, 14), blk, 0, stream>>>(jobs);
  }

  gemm_table_k<true><<<dim3(157, 8), blk, 0, stream>>>(E_q, 10000, WxTq, nullptr, XQf);
  gemm_table_k<true><<<dim3(8, 8), blk, 0, stream>>>(E_c, 500, WxTc, b_x, XCf);
  gemm_table_k<true><<<dim3(2, 8), blk, 0, stream>>>(E_qd, 101, WxTqd, nullptr, XQDf);
  gemm_table_k<true><<<dim3(2, 8), blk, 0, stream>>>(E_cd, 101, WxTcd, nullptr, XCDf);

  gemm_table2_k<<<dim3(157, 8), blk, 0, stream>>>(XQf, 10000, Ws1T, Ws2T,
                                                  nullptr, nullptr, XQS1, XQS2);
  gemm_table2_k<<<dim3(8, 8), blk, 0, stream>>>(XCf, 500, Ws1T, Ws2T,
                                                b_s1, b_s2, XCS1, XCS2);
  gemm_table2_k<<<dim3(2, 8), blk, 0, stream>>>(XQDf, 101, Ws1T, Ws2T,
                                                nullptr, nullptr, XQDS1, XQDS2);
  gemm_table2_k<<<dim3(2, 8), blk, 0, stream>>>(XCDf, 101, Ws1T, Ws2T,
                                                nullptr, nullptr, XCDS1, XCDS2);

  gemm_table_k<false><<<dim3(1, 8), blk, 0, stream>>>(E_corr, 2, WkiTco, b_ki, Kcorr);
  gemm_table_k<false><<<dim3(2, 8), blk, 0, stream>>>(E_qd, 101, WkiTqd, nullptr, Kqd);
  gemm_table_k<false><<<dim3(2, 8), blk, 0, stream>>>(E_cd, 101, WkiTcd, nullptr, Kcd);
  gemm_table_k<false><<<dim3(1, 8), blk, 0, stream>>>(E_corr, 2, Wp1hT, b_p1, P1c);
  gemm_table_k<false><<<dim3(1, 8), blk, 0, stream>>>(E_corr, 2, Wp2hT, b_p2, P2c);

  seqT_k<<<dim3(400), blk, 0, stream>>>(q_seq, c_seq, qd_seq, cd_seq, corr_seq,
                                        qT, cT, qdT, cdT, corrT);
  prologue_k<<<dim3(1024), blk, 0, stream>>>(h0, hb, flags);

  // persistent scan (cooperative for guaranteed co-residency; plain fallback)
  {
    const u16 *a0 = Ws1T, *a1 = Ws2T, *a2 = WkihT, *a3 = Wp1aT, *a4 = Wp2aT;
    const u16 *a5 = Kcorr, *a6 = Kqd, *a7 = Kcd, *a8 = P1c, *a9 = P2c;
    const u16 *a10 = XQS1, *a11 = XQS2, *a12 = XCS1, *a13 = XCS2;
    const u16 *a14 = XQDS1, *a15 = XQDS2, *a16 = XCDS1, *a17 = XCDS2;
    const int *a18 = qT, *a19 = cT, *a20 = qdT, *a21 = cdT, *a22 = corrT;
    const float *a23 = XQf, *a24 = XCf, *a25 = XQDf, *a26 = XCDf, *a27 = h0;
    u16 *a28 = sdf, *a29 = hb;
    float* a30 = dotpart;
    unsigned* a31 = flags;
    void* args[] = {&a0, &a1, &a2, &a3, &a4, &a5, &a6, &a7, &a8, &a9,
                    &a10, &a11, &a12, &a13, &a14, &a15, &a16, &a17,
                    &a18, &a19, &a20, &a21, &a22, &a23, &a24, &a25, &a26, &a27,
                    &a28, &a29, &a30, &a31};
    hipError_t e = hipLaunchCooperativeKernel((void*)scan_k, dim3(256), dim3(256),
                                              args, 0, stream);
    if (e != hipSuccess) {
      scan_k<<<dim3(256), dim3(256), 0, stream>>>(Ws1T, Ws2T, WkihT, Wp1aT, Wp2aT,
                                                  Kcorr, Kqd, Kcd, P1c, P2c,
                                                  XQS1, XQS2, XCS1, XCS2,
                                                  XQDS1, XQDS2, XCDS1, XCDS2,
                                                  qT, cT, qdT, cdT, corrT,
                                                  XQf, XCf, XQDf, XCDf, h0,
                                                  sdf, hb, dotpart, flags);
    }
  }

  finalize_k<<<dim3(400), blk, 0, stream>>>(dotpart, y);
}